// Round 2
// 1842.323 us; speedup vs baseline: 1.6611x; 1.6611x over previous
//
#include <hip/hip_runtime.h>
#include <math.h>

#define S_LEN 1024
#define B_DIM 128
#define D_DIM 64
#define H_DIM 128
#define O_DIM 512
#define M_DIM 131072         // B*S

// -------- kernel 1: encoder  pt[t*B*H + b*H + h] = x[b,t,:]·We[h,:] + be[h]
__global__ __launch_bounds__(256) void enc_kernel(
    const float* __restrict__ x, const float* __restrict__ We,
    const float* __restrict__ be, float* __restrict__ pt) {
  __shared__ __align__(16) float xs[128];
  int tid = threadIdx.x;
  long q0 = (long)blockIdx.x * 2;          // two (b,t) pairs per block
  if (tid < 128) xs[tid] = x[q0 * 64 + tid];
  __syncthreads();
  int half = tid >> 7;                     // 0/1 -> which pair
  int h = tid & 127;
  long q = q0 + half;                      // q = b*S + t
  const float4* w4 = (const float4*)(We + (long)h * 64);
  const float4* x4 = (const float4*)(xs + half * 64);
  float acc = 0.f;
#pragma unroll
  for (int i = 0; i < 16; ++i) {
    float4 a = x4[i];
    float4 b = w4[i];
    acc += a.x * b.x + a.y * b.y + a.z * b.z + a.w * b.w;
  }
  acc += be[h];
  int b = (int)(q >> 10);
  int t = (int)(q & 1023);
  pt[(long)t * 16384 + b * 128 + h] = acc;
}

// -------- kernel 2: is_rep[t] = all(x[:,t,:] == x[:,t-1,:]); rep[0]=0
__global__ __launch_bounds__(256) void rep_kernel(const float* __restrict__ x,
                                                  int* __restrict__ rep) {
  int t = blockIdx.x;
  int tid = threadIdx.x;
  if (t == 0) {
    if (tid == 0) rep[0] = 0;
    return;
  }
  int ok = 1;
  for (int j = tid; j < B_DIM * D_DIM; j += 256) {
    int b = j >> 6, d = j & 63;
    long i1 = (long)b * S_LEN * 64 + (long)t * 64 + d;
    if (x[i1] != x[i1 - 64]) ok = 0;
  }
  ok = __syncthreads_and(ok);
  if (tid == 0) rep[t] = ok;
}

// -------- kernel 3: sequential scan over t, one thread per (b,h)
//          (math kept bit-identical to the passing baseline)
__global__ __launch_bounds__(64) void scan_kernel(
    const float* __restrict__ pt, const float* __restrict__ omega,
    const int* __restrict__ rep, float* __restrict__ ph_out,
    float* __restrict__ wb_out) {
  __shared__ int reps[1024];
  int tid = threadIdx.x;
  for (int i = tid; i < 1024; i += 64) reps[i] = rep[i];
  __syncthreads();
  int g = blockIdx.x * 64 + tid;           // 0..16383
  int b = g >> 7, h = g & 127;
  float om = omega[h];
  float ph = 0.f, wb = 0.f;
  long obase = (long)b * (S_LEN * 128) + h;
  float cur[16], nxt[16];
#pragma unroll
  for (int u = 0; u < 16; ++u) cur[u] = pt[(long)u * 16384 + g];
  for (int t0 = 0; t0 < S_LEN; t0 += 16) {
#pragma unroll
    for (int u = 0; u < 16; ++u) {
      int tl = t0 + 16 + u;
      if (tl > 1023) tl = 1023;
      nxt[u] = pt[(long)tl * 16384 + g];
    }
#pragma unroll
    for (int u = 0; u < 16; ++u) {
      int t = t0 + u;
      float th = cur[u];
      wb += 0.015625f;
      ph = ph + om - sinf(th - ph) + 0.25f * sinf(wb);
      if (reps[t]) wb = wb + 0.25f * sinf(th - wb);
      ph_out[obase + (long)t * 128] = ph;
      wb_out[obase + (long)t * 128] = wb;
    }
#pragma unroll
    for (int u = 0; u < 16; ++u) cur[u] = nxt[u];
  }
}

// -------- kernel 4: MFMA readout GEMM, feats fused from ph/wb hist.
// C[M,512] = F[M,1152]_bf16 · Wrb[1152,512]_bf16  (+ br)
// K-blocks f=0..8 of 128 h each:
//   f0 cos(ph) f1 sin(ph) f2 cos(ph/2) f3 sin(ph/2) f4 cos(wb) f5 sin(wb)
//   f6 hi(ph)*hi(w)   f7 lo(ph)*hi(w)   f8 hi(ph)*lo(w)   (split-bf16 ph·w)
// BM=128, BN=128, BK=64 (18 chunks), 256 thr = 4 waves (2x2), 4x4 frags of
// 16x16x32 bf16 per wave. LDS rows padded to 72 bf16 (144 B -> <=2-way bank).
typedef short bf16x8 __attribute__((ext_vector_type(8)));
typedef float f32x4 __attribute__((ext_vector_type(4)));

__device__ __forceinline__ unsigned short bf_rne(float x) {
  union { float f; unsigned u; } c;
  c.f = x;
  unsigned u = c.u;
  return (unsigned short)((u + 0x7fffu + ((u >> 16) & 1u)) >> 16);
}
__device__ __forceinline__ float bf_to_f(unsigned short h) {
  union { unsigned u; float f; } c;
  c.u = ((unsigned)h) << 16;
  return c.f;
}

__global__ __launch_bounds__(256) void out_mfma(
    const float* __restrict__ ph_hist, const float* __restrict__ wb_hist,
    const float* __restrict__ Wr, const float* __restrict__ br,
    float* __restrict__ out) {
  __shared__ __align__(16) unsigned short As[128 * 72];
  __shared__ __align__(16) unsigned short Bs[128 * 72];
  int tid = threadIdx.x;
  int lane = tid & 63;
  int wid = tid >> 6;
  int wm = wid >> 1, wn = wid & 1;         // 2x2 wave grid, 64x64 each
  long rBlock = (long)blockIdx.y * 128;
  int oBlock = blockIdx.x * 128;
  int l15 = lane & 15;
  int kq = lane >> 4;                      // 0..3 (k-group / row-group)
  int jq = tid & 15;                       // k-quad within BK: k = 4*jq
  int r0 = tid >> 4;                       // staging row base 0..15

  f32x4 acc[4][4];
#pragma unroll
  for (int mi = 0; mi < 4; ++mi)
#pragma unroll
    for (int ni = 0; ni < 4; ++ni) {
      acc[mi][ni][0] = 0.f; acc[mi][ni][1] = 0.f;
      acc[mi][ni][2] = 0.f; acc[mi][ni][3] = 0.f;
    }

  for (int kc = 0; kc < 18; ++kc) {
    int f = kc >> 1;
    int h0 = (kc & 1) * 64;
    __syncthreads();                       // previous chunk's reads done
    // ---- stage A: 128 rows x 64 k of feature f, half h0
    {
      const float* src = (f == 4 || f == 5) ? wb_hist : ph_hist;
#pragma unroll
      for (int i = 0; i < 8; ++i) {
        int row = r0 + 16 * i;
        float4 v = *(const float4*)&src[(rBlock + row) * 128 + h0 + 4 * jq];
        float e[4] = {v.x, v.y, v.z, v.w};
        unsigned short q[4];
        if (f == 6 || f == 8) {
#pragma unroll
          for (int j = 0; j < 4; ++j) q[j] = bf_rne(e[j]);          // hi(ph)
        } else if (f == 7) {
#pragma unroll
          for (int j = 0; j < 4; ++j) {                             // lo(ph)
            unsigned short h = bf_rne(e[j]);
            q[j] = bf_rne(e[j] - bf_to_f(h));
          }
        } else if (f == 0 || f == 4) {
#pragma unroll
          for (int j = 0; j < 4; ++j) q[j] = bf_rne(__cosf(e[j]));
        } else if (f == 1 || f == 5) {
#pragma unroll
          for (int j = 0; j < 4; ++j) q[j] = bf_rne(__sinf(e[j]));
        } else if (f == 2) {
#pragma unroll
          for (int j = 0; j < 4; ++j) q[j] = bf_rne(__cosf(0.5f * e[j]));
        } else {  // f == 3
#pragma unroll
          for (int j = 0; j < 4; ++j) q[j] = bf_rne(__sinf(0.5f * e[j]));
        }
        uint2 p;
        p.x = (unsigned)q[0] | ((unsigned)q[1] << 16);
        p.y = (unsigned)q[2] | ((unsigned)q[3] << 16);
        *(uint2*)&As[row * 72 + 4 * jq] = p;
      }
    }
    // ---- stage B: 128 o x 64 k of Wr (bf16 / hi / lo)
    {
      int wcol = (f < 6 ? f * 128 : 768) + h0 + 4 * jq;
#pragma unroll
      for (int i = 0; i < 8; ++i) {
        int row = r0 + 16 * i;
        float4 v = *(const float4*)&Wr[(long)(oBlock + row) * 896 + wcol];
        float e[4] = {v.x, v.y, v.z, v.w};
        unsigned short q[4];
        if (f == 8) {
#pragma unroll
          for (int j = 0; j < 4; ++j) {                             // lo(w)
            unsigned short h = bf_rne(e[j]);
            q[j] = bf_rne(e[j] - bf_to_f(h));
          }
        } else {
#pragma unroll
          for (int j = 0; j < 4; ++j) q[j] = bf_rne(e[j]);          // hi(w)
        }
        uint2 p;
        p.x = (unsigned)q[0] | ((unsigned)q[1] << 16);
        p.y = (unsigned)q[2] | ((unsigned)q[3] << 16);
        *(uint2*)&Bs[row * 72 + 4 * jq] = p;
      }
    }
    __syncthreads();
    // ---- compute: 2 k-steps of 32, 16 MFMA each
#pragma unroll
    for (int ks = 0; ks < 2; ++ks) {
      int kk = ks * 32 + kq * 8;
      bf16x8 a[4], b[4];
#pragma unroll
      for (int mi = 0; mi < 4; ++mi)
        a[mi] = *(const bf16x8*)&As[(wm * 64 + mi * 16 + l15) * 72 + kk];
#pragma unroll
      for (int ni = 0; ni < 4; ++ni)
        b[ni] = *(const bf16x8*)&Bs[(wn * 64 + ni * 16 + l15) * 72 + kk];
#pragma unroll
      for (int mi = 0; mi < 4; ++mi)
#pragma unroll
        for (int ni = 0; ni < 4; ++ni)
          acc[mi][ni] = __builtin_amdgcn_mfma_f32_16x16x32_bf16(
              a[mi], b[ni], acc[mi][ni], 0, 0, 0);
    }
  }
  // ---- epilogue: bias + store (C/D: col=lane&15, row=(lane>>4)*4+reg)
#pragma unroll
  for (int ni = 0; ni < 4; ++ni) {
    int col = oBlock + wn * 64 + ni * 16 + l15;
    float bias = br[col];
#pragma unroll
    for (int mi = 0; mi < 4; ++mi) {
      long row = rBlock + wm * 64 + mi * 16 + kq * 4;
#pragma unroll
      for (int r = 0; r < 4; ++r)
        out[(row + r) * 512 + col] = acc[mi][ni][r] + bias;
    }
  }
}

extern "C" void kernel_launch(void* const* d_in, const int* in_sizes, int n_in,
                              void* d_out, int out_size, void* d_ws,
                              size_t ws_size, hipStream_t stream) {
  (void)in_sizes; (void)n_in; (void)d_ws; (void)ws_size; (void)out_size;
  const float* x = (const float*)d_in[0];
  const float* We = (const float*)d_in[1];
  const float* be = (const float*)d_in[2];
  const float* omega = (const float*)d_in[3];
  const float* Wr = (const float*)d_in[4];
  const float* br = (const float*)d_in[5];

  float* out = (float*)d_out;
  float* logits = out;                               // [B,S,O] = [M,512]
  float* ph_hist = out + (long)M_DIM * O_DIM;        // [B,S,H] = [M,128]
  float* wb_hist = ph_hist + (long)M_DIM * H_DIM;    // [B,S,H]

  // scratch inside the (later overwritten) logits region:
  float* pt = logits;                                // [S,B,H] 16.8M floats
  int* rep = (int*)(logits + 40l * 1024 * 1024);     // 1024 ints, past pt

  enc_kernel<<<M_DIM / 2, 256, 0, stream>>>(x, We, be, pt);
  rep_kernel<<<S_LEN, 256, 0, stream>>>(x, rep);
  scan_kernel<<<256, 64, 0, stream>>>(pt, omega, rep, ph_hist, wb_hist);
  dim3 g(O_DIM / 128, M_DIM / 128);                  // col fastest: A reuse
  out_mfma<<<g, 256, 0, stream>>>(ph_hist, wb_hist, Wr, br, logits);
}

// Round 3
// 1172.379 us; speedup vs baseline: 2.6103x; 1.5714x over previous
//
#include <hip/hip_runtime.h>
#include <math.h>

#define S_LEN 1024
#define B_DIM 128
#define D_DIM 64
#define H_DIM 128
#define O_DIM 512
#define M_DIM 131072         // B*S

// -------- kernel 1: encoder, 16 (b,t) pairs per block, We row in regs
__global__ __launch_bounds__(256) void enc_kernel(
    const float* __restrict__ x, const float* __restrict__ We,
    const float* __restrict__ be, float* __restrict__ pt) {
  __shared__ __align__(16) float xs[1024];
  int tid = threadIdx.x;
  long q0 = (long)blockIdx.x * 16;
  for (int i = tid; i < 1024; i += 256) xs[i] = x[q0 * 64 + i];
  __syncthreads();
  int h = tid & 127;
  int pg = tid >> 7;                       // 0/1: which 8 pairs
  float4 w[16];
  const float4* w4 = (const float4*)(We + (long)h * 64);
#pragma unroll
  for (int i = 0; i < 16; ++i) w[i] = w4[i];
  float bias = be[h];
#pragma unroll
  for (int j = 0; j < 8; ++j) {
    int p = pg * 8 + j;
    const float4* x4 = (const float4*)(xs + p * 64);
    float acc = 0.f;
#pragma unroll
    for (int i = 0; i < 16; ++i) {
      float4 a = x4[i];
      float4 b = w[i];
      acc += a.x * b.x + a.y * b.y + a.z * b.z + a.w * b.w;
    }
    long q = q0 + p;
    int bb = (int)(q >> 10), t = (int)(q & 1023);
    pt[(long)t * 16384 + bb * 128 + h] = acc + bias;
  }
}

// -------- kernel 2: is_rep[t] = all(x[:,t,:] == x[:,t-1,:]); rep[0]=0
__global__ __launch_bounds__(256) void rep_kernel(const float* __restrict__ x,
                                                  int* __restrict__ rep) {
  int t = blockIdx.x;
  int tid = threadIdx.x;
  if (t == 0) {
    if (tid == 0) rep[0] = 0;
    return;
  }
  int ok = 1;
  for (int j = tid; j < B_DIM * D_DIM; j += 256) {
    int b = j >> 6, d = j & 63;
    long i1 = (long)b * S_LEN * 64 + (long)t * 64 + d;
    if (x[i1] != x[i1 - 64]) ok = 0;
  }
  ok = __syncthreads_and(ok);
  if (tid == 0) rep[t] = ok;
}

// -------- kernel 3: sequential scan over t (math bit-identical; untouched)
__global__ __launch_bounds__(64) void scan_kernel(
    const float* __restrict__ pt, const float* __restrict__ omega,
    const int* __restrict__ rep, float* __restrict__ ph_out,
    float* __restrict__ wb_out) {
  __shared__ int reps[1024];
  int tid = threadIdx.x;
  for (int i = tid; i < 1024; i += 64) reps[i] = rep[i];
  __syncthreads();
  int g = blockIdx.x * 64 + tid;           // 0..16383
  int b = g >> 7, h = g & 127;
  float om = omega[h];
  float ph = 0.f, wb = 0.f;
  long obase = (long)b * (S_LEN * 128) + h;
  float cur[16], nxt[16];
#pragma unroll
  for (int u = 0; u < 16; ++u) cur[u] = pt[(long)u * 16384 + g];
  for (int t0 = 0; t0 < S_LEN; t0 += 16) {
#pragma unroll
    for (int u = 0; u < 16; ++u) {
      int tl = t0 + 16 + u;
      if (tl > 1023) tl = 1023;
      nxt[u] = pt[(long)tl * 16384 + g];
    }
#pragma unroll
    for (int u = 0; u < 16; ++u) {
      int t = t0 + u;
      float th = cur[u];
      wb += 0.015625f;
      ph = ph + om - sinf(th - ph) + 0.25f * sinf(wb);
      if (reps[t]) wb = wb + 0.25f * sinf(th - wb);
      ph_out[obase + (long)t * 128] = ph;
      wb_out[obase + (long)t * 128] = wb;
    }
#pragma unroll
    for (int u = 0; u < 16; ++u) cur[u] = nxt[u];
  }
}

// -------- kernel 4: MFMA readout GEMM, fused features, grouped staging.
// C[M,512] = F[M,1152]_bf16 · Wrb[1152,512]_bf16 (+ br)
// Per h-half (64 k), 4 barrier-groups:
//   G0 {f0=cos(ph), f1=sin(ph)}   one __sincosf pass
//   G1 {f2=cos(.5ph), f3=sin(.5ph)}
//   G2 {f6=hi(ph)·hi(w7), f7=lo(ph)·hi(w7), f8=hi(ph)·lo(w7)}  (A/B aliased)
//   G3 {f4=cos(wb), f5=sin(wb)}
// BM=BN=128, 256 thr = 2x2 waves, 4x4 frags of 16x16x32 bf16.
// LDS: 4 slots [128][72] bf16 (144B row stride: 16B-aligned, ~min bank use).
typedef short bf16x8 __attribute__((ext_vector_type(8)));
typedef float f32x4 __attribute__((ext_vector_type(4)));

__device__ __forceinline__ unsigned short bf_rne(float x) {
  union { float f; unsigned u; } c;
  c.f = x;
  unsigned u = c.u;
  return (unsigned short)((u + 0x7fffu + ((u >> 16) & 1u)) >> 16);
}
__device__ __forceinline__ float bf_to_f(unsigned short h) {
  union { unsigned u; float f; } c;
  c.u = ((unsigned)h) << 16;
  return c.f;
}

__global__ __launch_bounds__(256) void out_mfma(
    const float* __restrict__ ph_hist, const float* __restrict__ wb_hist,
    const float* __restrict__ Wr, const float* __restrict__ br,
    float* __restrict__ out) {
  __shared__ __align__(16) unsigned short As0[128 * 72];
  __shared__ __align__(16) unsigned short As1[128 * 72];
  __shared__ __align__(16) unsigned short Bs0[128 * 72];
  __shared__ __align__(16) unsigned short Bs1[128 * 72];
  int tid = threadIdx.x;
  int lane = tid & 63;
  int wid = tid >> 6;
  int wm = wid >> 1, wn = wid & 1;         // 2x2 wave grid, 64x64 each
  // XCD chunk swizzle: 4096 blocks, xcd=bid%8 gets contiguous newbid chunk;
  // the 4 col-blocks of a row-block share one XCD's L2 (A-tile reuse).
  int nb = ((blockIdx.x & 7) << 9) | (blockIdx.x >> 3);
  long rBlock = (long)(nb >> 2) * 128;
  int oBlock = (nb & 3) * 128;
  int l15 = lane & 15;
  int kq = lane >> 4;                      // 0..3
  int jq = tid & 15;                       // k-quad: cols 4*jq..+4
  int r0 = tid >> 4;                       // staging row base 0..15

  f32x4 acc[4][4];
#pragma unroll
  for (int mi = 0; mi < 4; ++mi)
#pragma unroll
    for (int ni = 0; ni < 4; ++ni) {
      acc[mi][ni][0] = 0.f; acc[mi][ni][1] = 0.f;
      acc[mi][ni][2] = 0.f; acc[mi][ni][3] = 0.f;
    }

  // 16 MFMA x 2 k-steps on one (A,B) slot pair
  auto mm = [&](const unsigned short* A, const unsigned short* Bsl) {
#pragma unroll
    for (int ks = 0; ks < 2; ++ks) {
      int kk = ks * 32 + kq * 8;
      bf16x8 a[4], b[4];
#pragma unroll
      for (int mi = 0; mi < 4; ++mi)
        a[mi] = *(const bf16x8*)&A[(wm * 64 + mi * 16 + l15) * 72 + kk];
#pragma unroll
      for (int ni = 0; ni < 4; ++ni)
        b[ni] = *(const bf16x8*)&Bsl[(wn * 64 + ni * 16 + l15) * 72 + kk];
#pragma unroll
      for (int mi = 0; mi < 4; ++mi)
#pragma unroll
        for (int ni = 0; ni < 4; ++ni)
          acc[mi][ni] = __builtin_amdgcn_mfma_f32_16x16x32_bf16(
              a[mi], b[ni], acc[mi][ni], 0, 0, 0);
    }
  };

  // stage one Wr chunk (plain bf16) into slot
  auto stageB = [&](int fbase, int h0, unsigned short* slot) {
#pragma unroll
    for (int i = 0; i < 8; ++i) {
      int row = r0 + 16 * i;
      float4 v = *(const float4*)&Wr[(long)(oBlock + row) * 896 + fbase + h0 + 4 * jq];
      uint2 p;
      p.x = (unsigned)bf_rne(v.x) | ((unsigned)bf_rne(v.y) << 16);
      p.y = (unsigned)bf_rne(v.z) | ((unsigned)bf_rne(v.w) << 16);
      *(uint2*)&slot[row * 72 + 4 * jq] = p;
    }
  };

  for (int half = 0; half < 2; ++half) {
    int h0 = half * 64;
    float4 pha[8];
    // ---- G0: load ph (kept in regs for G1/G2); f0=cos, f1=sin
    __syncthreads();
#pragma unroll
    for (int i = 0; i < 8; ++i)
      pha[i] = *(const float4*)&ph_hist[(rBlock + r0 + 16 * i) * 128 + h0 + 4 * jq];
#pragma unroll
    for (int i = 0; i < 8; ++i) {
      float e[4] = {pha[i].x, pha[i].y, pha[i].z, pha[i].w};
      unsigned short qc[4], qs[4];
#pragma unroll
      for (int j = 0; j < 4; ++j) {
        float s, c;
        __sincosf(e[j], &s, &c);
        qc[j] = bf_rne(c); qs[j] = bf_rne(s);
      }
      int row = r0 + 16 * i;
      uint2 pc, ps;
      pc.x = (unsigned)qc[0] | ((unsigned)qc[1] << 16);
      pc.y = (unsigned)qc[2] | ((unsigned)qc[3] << 16);
      ps.x = (unsigned)qs[0] | ((unsigned)qs[1] << 16);
      ps.y = (unsigned)qs[2] | ((unsigned)qs[3] << 16);
      *(uint2*)&As0[row * 72 + 4 * jq] = pc;
      *(uint2*)&As1[row * 72 + 4 * jq] = ps;
    }
    stageB(0 * 128, h0, Bs0);
    stageB(1 * 128, h0, Bs1);
    __syncthreads();
    mm(As0, Bs0);
    mm(As1, Bs1);

    // ---- G1: f2=cos(ph/2), f3=sin(ph/2) from kept ph
    __syncthreads();
#pragma unroll
    for (int i = 0; i < 8; ++i) {
      float e[4] = {pha[i].x, pha[i].y, pha[i].z, pha[i].w};
      unsigned short qc[4], qs[4];
#pragma unroll
      for (int j = 0; j < 4; ++j) {
        float s, c;
        __sincosf(0.5f * e[j], &s, &c);
        qc[j] = bf_rne(c); qs[j] = bf_rne(s);
      }
      int row = r0 + 16 * i;
      uint2 pc, ps;
      pc.x = (unsigned)qc[0] | ((unsigned)qc[1] << 16);
      pc.y = (unsigned)qc[2] | ((unsigned)qc[3] << 16);
      ps.x = (unsigned)qs[0] | ((unsigned)qs[1] << 16);
      ps.y = (unsigned)qs[2] | ((unsigned)qs[3] << 16);
      *(uint2*)&As0[row * 72 + 4 * jq] = pc;
      *(uint2*)&As1[row * 72 + 4 * jq] = ps;
    }
    stageB(2 * 128, h0, Bs0);
    stageB(3 * 128, h0, Bs1);
    __syncthreads();
    mm(As0, Bs0);
    mm(As1, Bs1);

    // ---- G2: split ph·w7: A0=hi(ph), A1=lo(ph); B0=hi(w7), B1=lo(w7)
    __syncthreads();
#pragma unroll
    for (int i = 0; i < 8; ++i) {
      float e[4] = {pha[i].x, pha[i].y, pha[i].z, pha[i].w};
      unsigned short qh[4], ql[4];
#pragma unroll
      for (int j = 0; j < 4; ++j) {
        qh[j] = bf_rne(e[j]);
        ql[j] = bf_rne(e[j] - bf_to_f(qh[j]));
      }
      int row = r0 + 16 * i;
      uint2 ph2, pl2;
      ph2.x = (unsigned)qh[0] | ((unsigned)qh[1] << 16);
      ph2.y = (unsigned)qh[2] | ((unsigned)qh[3] << 16);
      pl2.x = (unsigned)ql[0] | ((unsigned)ql[1] << 16);
      pl2.y = (unsigned)ql[2] | ((unsigned)ql[3] << 16);
      *(uint2*)&As0[row * 72 + 4 * jq] = ph2;
      *(uint2*)&As1[row * 72 + 4 * jq] = pl2;
    }
#pragma unroll
    for (int i = 0; i < 8; ++i) {          // w7 hi+lo from one load pass
      int row = r0 + 16 * i;
      float4 v = *(const float4*)&Wr[(long)(oBlock + row) * 896 + 768 + h0 + 4 * jq];
      float e[4] = {v.x, v.y, v.z, v.w};
      unsigned short qh[4], ql[4];
#pragma unroll
      for (int j = 0; j < 4; ++j) {
        qh[j] = bf_rne(e[j]);
        ql[j] = bf_rne(e[j] - bf_to_f(qh[j]));
      }
      uint2 ph2, pl2;
      ph2.x = (unsigned)qh[0] | ((unsigned)qh[1] << 16);
      ph2.y = (unsigned)qh[2] | ((unsigned)qh[3] << 16);
      pl2.x = (unsigned)ql[0] | ((unsigned)ql[1] << 16);
      pl2.y = (unsigned)ql[2] | ((unsigned)ql[3] << 16);
      *(uint2*)&Bs0[row * 72 + 4 * jq] = ph2;
      *(uint2*)&Bs1[row * 72 + 4 * jq] = pl2;
    }
    __syncthreads();
    mm(As0, Bs0);   // f6: hi·hi
    mm(As1, Bs0);   // f7: lo·hi
    mm(As0, Bs1);   // f8: hi·lo

    // ---- G3: f4=cos(wb), f5=sin(wb)
    __syncthreads();
#pragma unroll
    for (int i = 0; i < 8; ++i)
      pha[i] = *(const float4*)&wb_hist[(rBlock + r0 + 16 * i) * 128 + h0 + 4 * jq];
#pragma unroll
    for (int i = 0; i < 8; ++i) {
      float e[4] = {pha[i].x, pha[i].y, pha[i].z, pha[i].w};
      unsigned short qc[4], qs[4];
#pragma unroll
      for (int j = 0; j < 4; ++j) {
        float s, c;
        __sincosf(e[j], &s, &c);
        qc[j] = bf_rne(c); qs[j] = bf_rne(s);
      }
      int row = r0 + 16 * i;
      uint2 pc, ps;
      pc.x = (unsigned)qc[0] | ((unsigned)qc[1] << 16);
      pc.y = (unsigned)qc[2] | ((unsigned)qc[3] << 16);
      ps.x = (unsigned)qs[0] | ((unsigned)qs[1] << 16);
      ps.y = (unsigned)qs[2] | ((unsigned)qs[3] << 16);
      *(uint2*)&As0[row * 72 + 4 * jq] = pc;
      *(uint2*)&As1[row * 72 + 4 * jq] = ps;
    }
    stageB(4 * 128, h0, Bs0);
    stageB(5 * 128, h0, Bs1);
    __syncthreads();
    mm(As0, Bs0);
    mm(As1, Bs1);
  }

  // ---- epilogue: bias + store (C/D: col=lane&15, row=(lane>>4)*4+reg)
#pragma unroll
  for (int ni = 0; ni < 4; ++ni) {
    int col = oBlock + wn * 64 + ni * 16 + l15;
    float bias = br[col];
#pragma unroll
    for (int mi = 0; mi < 4; ++mi) {
      long row = rBlock + wm * 64 + mi * 16 + kq * 4;
#pragma unroll
      for (int r = 0; r < 4; ++r)
        out[(row + r) * 512 + col] = acc[mi][ni][r] + bias;
    }
  }
}

extern "C" void kernel_launch(void* const* d_in, const int* in_sizes, int n_in,
                              void* d_out, int out_size, void* d_ws,
                              size_t ws_size, hipStream_t stream) {
  (void)in_sizes; (void)n_in; (void)d_ws; (void)ws_size; (void)out_size;
  const float* x = (const float*)d_in[0];
  const float* We = (const float*)d_in[1];
  const float* be = (const float*)d_in[2];
  const float* omega = (const float*)d_in[3];
  const float* Wr = (const float*)d_in[4];
  const float* br = (const float*)d_in[5];

  float* out = (float*)d_out;
  float* logits = out;                               // [B,S,O] = [M,512]
  float* ph_hist = out + (long)M_DIM * O_DIM;        // [B,S,H] = [M,128]
  float* wb_hist = ph_hist + (long)M_DIM * H_DIM;    // [B,S,H]

  // scratch inside the (later overwritten) logits region:
  float* pt = logits;                                // [S,B,H] 16.8M floats
  int* rep = (int*)(logits + 40l * 1024 * 1024);     // 1024 ints, past pt

  enc_kernel<<<M_DIM / 16, 256, 0, stream>>>(x, We, be, pt);
  rep_kernel<<<S_LEN, 256, 0, stream>>>(x, rep);
  scan_kernel<<<256, 64, 0, stream>>>(pt, omega, rep, ph_hist, wb_hist);
  out_mfma<<<4096, 256, 0, stream>>>(ph_hist, wb_hist, Wr, br, logits);
}

// Round 5
// 1130.131 us; speedup vs baseline: 2.7079x; 1.0374x over previous
//
#include <hip/hip_runtime.h>
#include <math.h>

#define S_LEN 1024
#define B_DIM 128
#define D_DIM 64
#define H_DIM 128
#define O_DIM 512
#define M_DIM 131072         // B*S

// -------- kernel 1: encoder, 16 (b,t) pairs per block, We row in regs
__global__ __launch_bounds__(256) void enc_kernel(
    const float* __restrict__ x, const float* __restrict__ We,
    const float* __restrict__ be, float* __restrict__ pt) {
  __shared__ __align__(16) float xs[1024];
  int tid = threadIdx.x;
  long q0 = (long)blockIdx.x * 16;
  for (int i = tid; i < 1024; i += 256) xs[i] = x[q0 * 64 + i];
  __syncthreads();
  int h = tid & 127;
  int pg = tid >> 7;                       // 0/1: which 8 pairs
  float4 w[16];
  const float4* w4 = (const float4*)(We + (long)h * 64);
#pragma unroll
  for (int i = 0; i < 16; ++i) w[i] = w4[i];
  float bias = be[h];
#pragma unroll
  for (int j = 0; j < 8; ++j) {
    int p = pg * 8 + j;
    const float4* x4 = (const float4*)(xs + p * 64);
    float acc = 0.f;
#pragma unroll
    for (int i = 0; i < 16; ++i) {
      float4 a = x4[i];
      float4 b = w[i];
      acc += a.x * b.x + a.y * b.y + a.z * b.z + a.w * b.w;
    }
    long q = q0 + p;
    int bb = (int)(q >> 10), t = (int)(q & 1023);
    pt[(long)t * 16384 + bb * 128 + h] = acc + bias;
  }
}

// -------- kernel 2: is_rep[t] = all(x[:,t,:] == x[:,t-1,:]); rep[0]=0
__global__ __launch_bounds__(256) void rep_kernel(const float* __restrict__ x,
                                                  int* __restrict__ rep) {
  int t = blockIdx.x;
  int tid = threadIdx.x;
  if (t == 0) {
    if (tid == 0) rep[0] = 0;
    return;
  }
  int ok = 1;
  for (int j = tid; j < B_DIM * D_DIM; j += 256) {
    int b = j >> 6, d = j & 63;
    long i1 = (long)b * S_LEN * 64 + (long)t * 64 + d;
    if (x[i1] != x[i1 - 64]) ok = 0;
  }
  ok = __syncthreads_and(ok);
  if (tid == 0) rep[t] = ok;
}

// -------- kernel 3: sequential scan over t (math bit-identical; untouched)
__global__ __launch_bounds__(64) void scan_kernel(
    const float* __restrict__ pt, const float* __restrict__ omega,
    const int* __restrict__ rep, float* __restrict__ ph_out,
    float* __restrict__ wb_out) {
  __shared__ int reps[1024];
  int tid = threadIdx.x;
  for (int i = tid; i < 1024; i += 64) reps[i] = rep[i];
  __syncthreads();
  int g = blockIdx.x * 64 + tid;           // 0..16383
  int b = g >> 7, h = g & 127;
  float om = omega[h];
  float ph = 0.f, wb = 0.f;
  long obase = (long)b * (S_LEN * 128) + h;
  float cur[16], nxt[16];
#pragma unroll
  for (int u = 0; u < 16; ++u) cur[u] = pt[(long)u * 16384 + g];
  for (int t0 = 0; t0 < S_LEN; t0 += 16) {
#pragma unroll
    for (int u = 0; u < 16; ++u) {
      int tl = t0 + 16 + u;
      if (tl > 1023) tl = 1023;
      nxt[u] = pt[(long)tl * 16384 + g];
    }
#pragma unroll
    for (int u = 0; u < 16; ++u) {
      int t = t0 + u;
      float th = cur[u];
      wb += 0.015625f;
      ph = ph + om - sinf(th - ph) + 0.25f * sinf(wb);
      if (reps[t]) wb = wb + 0.25f * sinf(th - wb);
      ph_out[obase + (long)t * 128] = ph;
      wb_out[obase + (long)t * 128] = wb;
    }
#pragma unroll
    for (int u = 0; u < 16; ++u) cur[u] = nxt[u];
  }
}

// ---------------- bf16 helpers (RNE, bit-exact with previous rounds)
typedef short bf16x8 __attribute__((ext_vector_type(8)));
typedef float f32x4 __attribute__((ext_vector_type(4)));

__device__ __forceinline__ unsigned short bf_rne(float x) {
  union { float f; unsigned u; } c;
  c.f = x;
  unsigned u = c.u;
  return (unsigned short)((u + 0x7fffu + ((u >> 16) & 1u)) >> 16);
}
__device__ __forceinline__ float bf_to_f(unsigned short h) {
  union { unsigned u; float f; } c;
  c.u = ((unsigned)h) << 16;
  return c.f;
}

// Module-global scratch for pre-tiled bf16 Wr (1 MB). No d_ws dependency:
// allocated at module load, safe regardless of ws_size, graph-capture OK.
__device__ unsigned short g_Wrb[64 * 8192];

// -------- kernel 3.5: Wr -> bf16 tiles, once.
// Layout: tile (cb, c), c = half*8 + j; j: 0=w7hi 1=w7lo 2=f2 3=f3 4=f0 5=f1
// 6=f4 7=f5. Tile = [row 0..127][k 0..63] shorts (16 KB), rows = cols of C.
__global__ __launch_bounds__(256) void prep_wrb(const float* __restrict__ Wr) {
  int tile = blockIdx.x;                   // 0..63
  int cb = tile >> 4;
  int c = tile & 15;
  int half = (c >> 3) & 1;
  int j = c & 7;
  const int fmap[8] = {6, 6, 2, 3, 0, 1, 4, 5};   // f=6 -> col base 768 (=ph·w)
  int f = fmap[j];
  int tid = threadIdx.x;
  int row = tid >> 1;
  int k0 = (tid & 1) * 32;
  const float* src = Wr + (long)(cb * 128 + row) * 896 + f * 128 + half * 64 + k0;
  unsigned short* dst = g_Wrb + (long)tile * 8192 + row * 64 + k0;
  int lo = (j == 1);
#pragma unroll
  for (int i = 0; i < 8; ++i) {
    float4 v = *(const float4*)&src[i * 4];
    float e[4] = {v.x, v.y, v.z, v.w};
    unsigned short q[4];
#pragma unroll
    for (int t = 0; t < 4; ++t) {
      unsigned short hb = bf_rne(e[t]);
      q[t] = lo ? bf_rne(e[t] - bf_to_f(hb)) : hb;
    }
    uint2 p;
    p.x = (unsigned)q[0] | ((unsigned)q[1] << 16);
    p.y = (unsigned)q[2] | ((unsigned)q[3] << 16);
    *(uint2*)&dst[i * 4] = p;
  }
}

// -------- kernel 4: MFMA readout GEMM. B = pure copy of pre-tiled g_Wrb
// (loads issued one phase early), A = fused features with half-angle
// identities (one sincos covers f0..f3). Per half: 4 phases of
// {writeB; compute+store A; issue next B loads; barrier; MFMA; barrier}.
__global__ __launch_bounds__(256, 2) void out_mfma(
    const float* __restrict__ ph_hist, const float* __restrict__ wb_hist,
    const float* __restrict__ br, float* __restrict__ out) {
  __shared__ __align__(16) unsigned short As0[128 * 72];
  __shared__ __align__(16) unsigned short As1[128 * 72];
  __shared__ __align__(16) unsigned short Bs0[128 * 72];
  __shared__ __align__(16) unsigned short Bs1[128 * 72];
  int tid = threadIdx.x;
  int lane = tid & 63;
  int wid = tid >> 6;
  int wm = wid >> 1, wn = wid & 1;         // 2x2 wave grid, 64x64 each
  // XCD chunk swizzle (bijective: 4096 % 8 == 0)
  int nb = ((blockIdx.x & 7) << 9) | (blockIdx.x >> 3);
  long rBlock = (long)(nb >> 2) * 128;
  int cb = nb & 3;
  int oBlock = cb * 128;
  int l15 = lane & 15;
  int kq = lane >> 4;                      // 0..3
  int jq = tid & 15;                       // k-quad: cols 4*jq..+4
  int r0 = tid >> 4;                       // A staging row base 0..15
  int brow = tid >> 1;                     // B staging row 0..127
  int bk = (tid & 1) * 32;                 // B staging k half (shorts)

  const unsigned short* wsrc = g_Wrb + (long)cb * (16 * 8192);

  f32x4 acc[4][4];
#pragma unroll
  for (int mi = 0; mi < 4; ++mi)
#pragma unroll
    for (int ni = 0; ni < 4; ++ni) {
      acc[mi][ni][0] = 0.f; acc[mi][ni][1] = 0.f;
      acc[mi][ni][2] = 0.f; acc[mi][ni][3] = 0.f;
    }

  uint4 breg[8];                           // next-phase B chunks in flight
  auto loadB = [&](int p) {
    const uint4* s0 = (const uint4*)(wsrc + (long)(2 * p) * 8192 + tid * 32);
    const uint4* s1 = (const uint4*)(wsrc + (long)(2 * p + 1) * 8192 + tid * 32);
#pragma unroll
    for (int i = 0; i < 4; ++i) breg[i] = s0[i];
#pragma unroll
    for (int i = 0; i < 4; ++i) breg[4 + i] = s1[i];
  };
  auto writeB = [&]() {
#pragma unroll
    for (int i = 0; i < 4; ++i)
      *(uint4*)&Bs0[brow * 72 + bk + i * 8] = breg[i];
#pragma unroll
    for (int i = 0; i < 4; ++i)
      *(uint4*)&Bs1[brow * 72 + bk + i * 8] = breg[4 + i];
  };
  auto storeA = [&](int i, uint2 v0, uint2 v1) {
    *(uint2*)&As0[(r0 + 16 * i) * 72 + 4 * jq] = v0;
    *(uint2*)&As1[(r0 + 16 * i) * 72 + 4 * jq] = v1;
  };
  auto pk = [&](float a, float b) -> unsigned {
    return (unsigned)bf_rne(a) | ((unsigned)bf_rne(b) << 16);
  };
  auto mm = [&](const unsigned short* A, const unsigned short* Bsl) {
#pragma unroll
    for (int ks = 0; ks < 2; ++ks) {
      int kk = ks * 32 + kq * 8;
      bf16x8 a[4], b[4];
#pragma unroll
      for (int mi = 0; mi < 4; ++mi)
        a[mi] = *(const bf16x8*)&A[(wm * 64 + mi * 16 + l15) * 72 + kk];
#pragma unroll
      for (int ni = 0; ni < 4; ++ni)
        b[ni] = *(const bf16x8*)&Bsl[(wn * 64 + ni * 16 + l15) * 72 + kk];
#pragma unroll
      for (int mi = 0; mi < 4; ++mi)
#pragma unroll
        for (int ni = 0; ni < 4; ++ni)
          acc[mi][ni] = __builtin_amdgcn_mfma_f32_16x16x32_bf16(
              a[mi], b[ni], acc[mi][ni], 0, 0, 0);
    }
  };

  float4 pha[8];
  // prologue: ph(half0) + first B chunk pair in flight
#pragma unroll
  for (int i = 0; i < 8; ++i)
    pha[i] = *(const float4*)&ph_hist[(rBlock + r0 + 16 * i) * 128 + 4 * jq];
  loadB(0);

#pragma unroll
  for (int half = 0; half < 2; ++half) {
    int h0 = half * 64;
    int pb = half * 4;

    // ---- p0: A = hi(ph), lo(ph); B = w7hi, w7lo
    __syncthreads();
    writeB();
#pragma unroll
    for (int i = 0; i < 8; ++i) {
      float e[4] = {pha[i].x, pha[i].y, pha[i].z, pha[i].w};
      unsigned short hb[4], lb[4];
#pragma unroll
      for (int t = 0; t < 4; ++t) {
        hb[t] = bf_rne(e[t]);
        lb[t] = bf_rne(e[t] - bf_to_f(hb[t]));
      }
      uint2 vh, vl;
      vh.x = (unsigned)hb[0] | ((unsigned)hb[1] << 16);
      vh.y = (unsigned)hb[2] | ((unsigned)hb[3] << 16);
      vl.x = (unsigned)lb[0] | ((unsigned)lb[1] << 16);
      vl.y = (unsigned)lb[2] | ((unsigned)lb[3] << 16);
      storeA(i, vh, vl);
    }
    loadB(pb + 1);
    __syncthreads();
    mm(As0, Bs0);   // f6: hi·hi
    mm(As1, Bs0);   // f7: lo·hi
    mm(As0, Bs1);   // f8: hi·lo

    // ---- p1: one sincos(ph/2): A = f2=cos, f3=sin; derive f0,f1 for p2
    __syncthreads();
    writeB();
    uint2 f0p[8], f1p[8];
#pragma unroll
    for (int i = 0; i < 8; ++i) {
      float e[4] = {pha[i].x, pha[i].y, pha[i].z, pha[i].w};
      float s2[4], c2[4], cf[4], sf[4];
#pragma unroll
      for (int t = 0; t < 4; ++t) {
        __sincosf(0.5f * e[t], &s2[t], &c2[t]);
        cf[t] = fmaf(-2.f * s2[t], s2[t], 1.f);   // cos(ph) = 1 - 2 sin^2(ph/2)
        sf[t] = 2.f * s2[t] * c2[t];              // sin(ph) = 2 sc
      }
      uint2 vc, vs;
      vc.x = pk(c2[0], c2[1]); vc.y = pk(c2[2], c2[3]);
      vs.x = pk(s2[0], s2[1]); vs.y = pk(s2[2], s2[3]);
      storeA(i, vc, vs);
      f0p[i].x = pk(cf[0], cf[1]); f0p[i].y = pk(cf[2], cf[3]);
      f1p[i].x = pk(sf[0], sf[1]); f1p[i].y = pk(sf[2], sf[3]);
    }
    loadB(pb + 2);
    __syncthreads();
    mm(As0, Bs0);   // f2
    mm(As1, Bs1);   // f3

    // ---- p2: A = f0,f1 (precomputed); prefetch wb for p3
    __syncthreads();
    writeB();
#pragma unroll
    for (int i = 0; i < 8; ++i) storeA(i, f0p[i], f1p[i]);
#pragma unroll
    for (int i = 0; i < 8; ++i)
      pha[i] = *(const float4*)&wb_hist[(rBlock + r0 + 16 * i) * 128 + h0 + 4 * jq];
    loadB(pb + 3);
    __syncthreads();
    mm(As0, Bs0);   // f0
    mm(As1, Bs1);   // f1

    // ---- p3: A = cos(wb), sin(wb); prefetch ph(half1) + its B chunks
    __syncthreads();
    writeB();
#pragma unroll
    for (int i = 0; i < 8; ++i) {
      float e[4] = {pha[i].x, pha[i].y, pha[i].z, pha[i].w};
      float sn[4], cs[4];
#pragma unroll
      for (int t = 0; t < 4; ++t) __sincosf(e[t], &sn[t], &cs[t]);
      uint2 vc, vs;
      vc.x = pk(cs[0], cs[1]); vc.y = pk(cs[2], cs[3]);
      vs.x = pk(sn[0], sn[1]); vs.y = pk(sn[2], sn[3]);
      storeA(i, vc, vs);
    }
    if (half == 0) {
#pragma unroll
      for (int i = 0; i < 8; ++i)
        pha[i] = *(const float4*)&ph_hist[(rBlock + r0 + 16 * i) * 128 + 64 + 4 * jq];
      loadB(4);
    }
    __syncthreads();
    mm(As0, Bs0);   // f4
    mm(As1, Bs1);   // f5
  }

  // ---- epilogue: bias + store (C/D: col=lane&15, row=(lane>>4)*4+reg)
#pragma unroll
  for (int ni = 0; ni < 4; ++ni) {
    int col = oBlock + wn * 64 + ni * 16 + l15;
    float bias = br[col];
#pragma unroll
    for (int mi = 0; mi < 4; ++mi) {
      long row = rBlock + wm * 64 + mi * 16 + kq * 4;
#pragma unroll
      for (int r = 0; r < 4; ++r)
        out[(row + r) * 512 + col] = acc[mi][ni][r] + bias;
    }
  }
}

extern "C" void kernel_launch(void* const* d_in, const int* in_sizes, int n_in,
                              void* d_out, int out_size, void* d_ws,
                              size_t ws_size, hipStream_t stream) {
  (void)in_sizes; (void)n_in; (void)d_ws; (void)ws_size; (void)out_size;
  const float* x = (const float*)d_in[0];
  const float* We = (const float*)d_in[1];
  const float* be = (const float*)d_in[2];
  const float* omega = (const float*)d_in[3];
  const float* Wr = (const float*)d_in[4];
  const float* br = (const float*)d_in[5];

  float* out = (float*)d_out;
  float* logits = out;                               // [B,S,O] = [M,512]
  float* ph_hist = out + (long)M_DIM * O_DIM;        // [B,S,H] = [M,128]
  float* wb_hist = ph_hist + (long)M_DIM * H_DIM;    // [B,S,H]

  // scratch inside the (later overwritten) logits region:
  float* pt = logits;                                // [S,B,H] 16.8M floats
  int* rep = (int*)(logits + 40l * 1024 * 1024);     // 1024 ints, past pt

  prep_wrb<<<64, 256, 0, stream>>>(Wr);
  enc_kernel<<<M_DIM / 16, 256, 0, stream>>>(x, We, be, pt);
  rep_kernel<<<S_LEN, 256, 0, stream>>>(x, rep);
  scan_kernel<<<256, 64, 0, stream>>>(pt, omega, rep, ph_hist, wb_hist);
  out_mfma<<<4096, 256, 0, stream>>>(ph_hist, wb_hist, br, logits);
}

// Round 6
// 1127.859 us; speedup vs baseline: 2.7133x; 1.0020x over previous
//
#include <hip/hip_runtime.h>
#include <math.h>

#define S_LEN 1024
#define B_DIM 128
#define D_DIM 64
#define H_DIM 128
#define O_DIM 512
#define M_DIM 131072         // B*S

// -------- kernel 1: encoder, 16 (b,t) pairs per block, We row in regs
__global__ __launch_bounds__(256) void enc_kernel(
    const float* __restrict__ x, const float* __restrict__ We,
    const float* __restrict__ be, float* __restrict__ pt) {
  __shared__ __align__(16) float xs[1024];
  int tid = threadIdx.x;
  long q0 = (long)blockIdx.x * 16;
  for (int i = tid; i < 1024; i += 256) xs[i] = x[q0 * 64 + i];
  __syncthreads();
  int h = tid & 127;
  int pg = tid >> 7;                       // 0/1: which 8 pairs
  float4 w[16];
  const float4* w4 = (const float4*)(We + (long)h * 64);
#pragma unroll
  for (int i = 0; i < 16; ++i) w[i] = w4[i];
  float bias = be[h];
#pragma unroll
  for (int j = 0; j < 8; ++j) {
    int p = pg * 8 + j;
    const float4* x4 = (const float4*)(xs + p * 64);
    float acc = 0.f;
#pragma unroll
    for (int i = 0; i < 16; ++i) {
      float4 a = x4[i];
      float4 b = w[i];
      acc += a.x * b.x + a.y * b.y + a.z * b.z + a.w * b.w;
    }
    long q = q0 + p;
    int bb = (int)(q >> 10), t = (int)(q & 1023);
    pt[(long)t * 16384 + bb * 128 + h] = acc + bias;
  }
}

// -------- kernel 2: is_rep[t] = all(x[:,t,:] == x[:,t-1,:]); rep[0]=0
__global__ __launch_bounds__(256) void rep_kernel(const float* __restrict__ x,
                                                  int* __restrict__ rep) {
  int t = blockIdx.x;
  int tid = threadIdx.x;
  if (t == 0) {
    if (tid == 0) rep[0] = 0;
    return;
  }
  int ok = 1;
  for (int j = tid; j < B_DIM * D_DIM; j += 256) {
    int b = j >> 6, d = j & 63;
    long i1 = (long)b * S_LEN * 64 + (long)t * 64 + d;
    if (x[i1] != x[i1 - 64]) ok = 0;
  }
  ok = __syncthreads_and(ok);
  if (tid == 0) rep[t] = ok;
}

// -------- kernel 3: sequential scan over t (math bit-identical; untouched)
__global__ __launch_bounds__(64) void scan_kernel(
    const float* __restrict__ pt, const float* __restrict__ omega,
    const int* __restrict__ rep, float* __restrict__ ph_out,
    float* __restrict__ wb_out) {
  __shared__ int reps[1024];
  int tid = threadIdx.x;
  for (int i = tid; i < 1024; i += 64) reps[i] = rep[i];
  __syncthreads();
  int g = blockIdx.x * 64 + tid;           // 0..16383
  int b = g >> 7, h = g & 127;
  float om = omega[h];
  float ph = 0.f, wb = 0.f;
  long obase = (long)b * (S_LEN * 128) + h;
  float cur[16], nxt[16];
#pragma unroll
  for (int u = 0; u < 16; ++u) cur[u] = pt[(long)u * 16384 + g];
  for (int t0 = 0; t0 < S_LEN; t0 += 16) {
#pragma unroll
    for (int u = 0; u < 16; ++u) {
      int tl = t0 + 16 + u;
      if (tl > 1023) tl = 1023;
      nxt[u] = pt[(long)tl * 16384 + g];
    }
#pragma unroll
    for (int u = 0; u < 16; ++u) {
      int t = t0 + u;
      float th = cur[u];
      wb += 0.015625f;
      ph = ph + om - sinf(th - ph) + 0.25f * sinf(wb);
      if (reps[t]) wb = wb + 0.25f * sinf(th - wb);
      ph_out[obase + (long)t * 128] = ph;
      wb_out[obase + (long)t * 128] = wb;
    }
#pragma unroll
    for (int u = 0; u < 16; ++u) cur[u] = nxt[u];
  }
}

// ---------------- bf16 helpers (RNE, bit-exact with previous rounds)
typedef short bf16x8 __attribute__((ext_vector_type(8)));
typedef float f32x4 __attribute__((ext_vector_type(4)));

__device__ __forceinline__ unsigned short bf_rne(float x) {
  union { float f; unsigned u; } c;
  c.f = x;
  unsigned u = c.u;
  return (unsigned short)((u + 0x7fffu + ((u >> 16) & 1u)) >> 16);
}
__device__ __forceinline__ float bf_to_f(unsigned short h) {
  union { unsigned u; float f; } c;
  c.u = ((unsigned)h) << 16;
  return c.f;
}

// Module-global scratch for pre-tiled bf16 Wr (1 MB). No d_ws dependency.
__device__ unsigned short g_Wrb[64 * 8192];

// -------- kernel 3.5: Wr -> bf16 tiles, once.
// Layout: tile (cb, c), c = half*8 + j; j: 0=w7hi 1=w7lo 2=f2 3=f3 4=f0 5=f1
// 6=f4 7=f5. Tile = [row 0..127][k 0..63] shorts (16 KB), rows = cols of C.
__global__ __launch_bounds__(256) void prep_wrb(const float* __restrict__ Wr) {
  int tile = blockIdx.x;                   // 0..63
  int cb = tile >> 4;
  int c = tile & 15;
  int half = (c >> 3) & 1;
  int j = c & 7;
  const int fmap[8] = {6, 6, 2, 3, 0, 1, 4, 5};   // f=6 -> col base 768 (=ph·w)
  int f = fmap[j];
  int tid = threadIdx.x;
  int row = tid >> 1;
  int k0 = (tid & 1) * 32;
  const float* src = Wr + (long)(cb * 128 + row) * 896 + f * 128 + half * 64 + k0;
  unsigned short* dst = g_Wrb + (long)tile * 8192 + row * 64 + k0;
  int lo = (j == 1);
#pragma unroll
  for (int i = 0; i < 8; ++i) {
    float4 v = *(const float4*)&src[i * 4];
    float e[4] = {v.x, v.y, v.z, v.w};
    unsigned short q[4];
#pragma unroll
    for (int t = 0; t < 4; ++t) {
      unsigned short hb = bf_rne(e[t]);
      q[t] = lo ? bf_rne(e[t] - bf_to_f(hb)) : hb;
    }
    uint2 p;
    p.x = (unsigned)q[0] | ((unsigned)q[1] << 16);
    p.y = (unsigned)q[2] | ((unsigned)q[3] << 16);
    *(uint2*)&dst[i * 4] = p;
  }
}

// -------- kernel 4: MFMA readout GEMM. B = pure copy of pre-tiled g_Wrb
// (loads issued one phase early), A = fused features with half-angle
// identities. Epilogue: per-wave LDS transpose -> full-line float4 stores.
__global__ __launch_bounds__(256, 2) void out_mfma(
    const float* __restrict__ ph_hist, const float* __restrict__ wb_hist,
    const float* __restrict__ br, float* __restrict__ out) {
  __shared__ __align__(16) unsigned short As0[128 * 72];
  __shared__ __align__(16) unsigned short As1[128 * 72];
  __shared__ __align__(16) unsigned short Bs0[128 * 72];
  __shared__ __align__(16) unsigned short Bs1[128 * 72];
  int tid = threadIdx.x;
  int lane = tid & 63;
  int wid = tid >> 6;
  int wm = wid >> 1, wn = wid & 1;         // 2x2 wave grid, 64x64 each
  // XCD chunk swizzle (bijective: 4096 % 8 == 0)
  int nb = ((blockIdx.x & 7) << 9) | (blockIdx.x >> 3);
  long rBlock = (long)(nb >> 2) * 128;
  int cb = nb & 3;
  int oBlock = cb * 128;
  int l15 = lane & 15;
  int kq = lane >> 4;                      // 0..3
  int jq = tid & 15;                       // k-quad: cols 4*jq..+4
  int r0 = tid >> 4;                       // A staging row base 0..15
  int brow = tid >> 1;                     // B staging row 0..127
  int bk = (tid & 1) * 32;                 // B staging k half (shorts)

  const unsigned short* wsrc = g_Wrb + (long)cb * (16 * 8192);

  f32x4 acc[4][4];
#pragma unroll
  for (int mi = 0; mi < 4; ++mi)
#pragma unroll
    for (int ni = 0; ni < 4; ++ni) {
      acc[mi][ni][0] = 0.f; acc[mi][ni][1] = 0.f;
      acc[mi][ni][2] = 0.f; acc[mi][ni][3] = 0.f;
    }

  uint4 breg[8];                           // next-phase B chunks in flight
  auto loadB = [&](int p) {
    const uint4* s0 = (const uint4*)(wsrc + (long)(2 * p) * 8192 + tid * 32);
    const uint4* s1 = (const uint4*)(wsrc + (long)(2 * p + 1) * 8192 + tid * 32);
#pragma unroll
    for (int i = 0; i < 4; ++i) breg[i] = s0[i];
#pragma unroll
    for (int i = 0; i < 4; ++i) breg[4 + i] = s1[i];
  };
  auto writeB = [&]() {
#pragma unroll
    for (int i = 0; i < 4; ++i)
      *(uint4*)&Bs0[brow * 72 + bk + i * 8] = breg[i];
#pragma unroll
    for (int i = 0; i < 4; ++i)
      *(uint4*)&Bs1[brow * 72 + bk + i * 8] = breg[4 + i];
  };
  auto storeA = [&](int i, uint2 v0, uint2 v1) {
    *(uint2*)&As0[(r0 + 16 * i) * 72 + 4 * jq] = v0;
    *(uint2*)&As1[(r0 + 16 * i) * 72 + 4 * jq] = v1;
  };
  auto pk = [&](float a, float b) -> unsigned {
    return (unsigned)bf_rne(a) | ((unsigned)bf_rne(b) << 16);
  };
  auto mm = [&](const unsigned short* A, const unsigned short* Bsl) {
    __builtin_amdgcn_s_setprio(1);
#pragma unroll
    for (int ks = 0; ks < 2; ++ks) {
      int kk = ks * 32 + kq * 8;
      bf16x8 a[4], b[4];
#pragma unroll
      for (int mi = 0; mi < 4; ++mi)
        a[mi] = *(const bf16x8*)&A[(wm * 64 + mi * 16 + l15) * 72 + kk];
#pragma unroll
      for (int ni = 0; ni < 4; ++ni)
        b[ni] = *(const bf16x8*)&Bsl[(wn * 64 + ni * 16 + l15) * 72 + kk];
#pragma unroll
      for (int mi = 0; mi < 4; ++mi)
#pragma unroll
        for (int ni = 0; ni < 4; ++ni)
          acc[mi][ni] = __builtin_amdgcn_mfma_f32_16x16x32_bf16(
              a[mi], b[ni], acc[mi][ni], 0, 0, 0);
    }
    __builtin_amdgcn_s_setprio(0);
  };

  float4 pha[8];
  // prologue: ph(half0) + first B chunk pair in flight
#pragma unroll
  for (int i = 0; i < 8; ++i)
    pha[i] = *(const float4*)&ph_hist[(rBlock + r0 + 16 * i) * 128 + 4 * jq];
  loadB(0);

#pragma unroll
  for (int half = 0; half < 2; ++half) {
    int h0 = half * 64;
    int pb = half * 4;

    // ---- p0: A = hi(ph), lo(ph); B = w7hi, w7lo
    __syncthreads();
    writeB();
#pragma unroll
    for (int i = 0; i < 8; ++i) {
      float e[4] = {pha[i].x, pha[i].y, pha[i].z, pha[i].w};
      unsigned short hb[4], lb[4];
#pragma unroll
      for (int t = 0; t < 4; ++t) {
        hb[t] = bf_rne(e[t]);
        lb[t] = bf_rne(e[t] - bf_to_f(hb[t]));
      }
      uint2 vh, vl;
      vh.x = (unsigned)hb[0] | ((unsigned)hb[1] << 16);
      vh.y = (unsigned)hb[2] | ((unsigned)hb[3] << 16);
      vl.x = (unsigned)lb[0] | ((unsigned)lb[1] << 16);
      vl.y = (unsigned)lb[2] | ((unsigned)lb[3] << 16);
      storeA(i, vh, vl);
    }
    loadB(pb + 1);
    __syncthreads();
    mm(As0, Bs0);   // f6: hi·hi
    mm(As1, Bs0);   // f7: lo·hi
    mm(As0, Bs1);   // f8: hi·lo

    // ---- p1: one sincos(ph/2): A = f2=cos, f3=sin; derive f0,f1 for p2
    __syncthreads();
    writeB();
    uint2 f0p[8], f1p[8];
#pragma unroll
    for (int i = 0; i < 8; ++i) {
      float e[4] = {pha[i].x, pha[i].y, pha[i].z, pha[i].w};
      float s2[4], c2[4], cf[4], sf[4];
#pragma unroll
      for (int t = 0; t < 4; ++t) {
        __sincosf(0.5f * e[t], &s2[t], &c2[t]);
        cf[t] = fmaf(-2.f * s2[t], s2[t], 1.f);   // cos(ph) = 1 - 2 sin^2(ph/2)
        sf[t] = 2.f * s2[t] * c2[t];              // sin(ph) = 2 sc
      }
      uint2 vc, vs;
      vc.x = pk(c2[0], c2[1]); vc.y = pk(c2[2], c2[3]);
      vs.x = pk(s2[0], s2[1]); vs.y = pk(s2[2], s2[3]);
      storeA(i, vc, vs);
      f0p[i].x = pk(cf[0], cf[1]); f0p[i].y = pk(cf[2], cf[3]);
      f1p[i].x = pk(sf[0], sf[1]); f1p[i].y = pk(sf[2], sf[3]);
    }
    loadB(pb + 2);
    __syncthreads();
    mm(As0, Bs0);   // f2
    mm(As1, Bs1);   // f3

    // ---- p2: A = f0,f1 (precomputed); prefetch wb for p3
    __syncthreads();
    writeB();
#pragma unroll
    for (int i = 0; i < 8; ++i) storeA(i, f0p[i], f1p[i]);
#pragma unroll
    for (int i = 0; i < 8; ++i)
      pha[i] = *(const float4*)&wb_hist[(rBlock + r0 + 16 * i) * 128 + h0 + 4 * jq];
    loadB(pb + 3);
    __syncthreads();
    mm(As0, Bs0);   // f0
    mm(As1, Bs1);   // f1

    // ---- p3: A = cos(wb), sin(wb); prefetch ph(half1) + its B chunks
    __syncthreads();
    writeB();
#pragma unroll
    for (int i = 0; i < 8; ++i) {
      float e[4] = {pha[i].x, pha[i].y, pha[i].z, pha[i].w};
      float sn[4], cs[4];
#pragma unroll
      for (int t = 0; t < 4; ++t) __sincosf(e[t], &sn[t], &cs[t]);
      uint2 vc, vs;
      vc.x = pk(cs[0], cs[1]); vc.y = pk(cs[2], cs[3]);
      vs.x = pk(sn[0], sn[1]); vs.y = pk(sn[2], sn[3]);
      storeA(i, vc, vs);
    }
    if (half == 0) {
#pragma unroll
      for (int i = 0; i < 8; ++i)
        pha[i] = *(const float4*)&ph_hist[(rBlock + r0 + 16 * i) * 128 + 64 + 4 * jq];
      loadB(4);
    }
    __syncthreads();
    mm(As0, Bs0);   // f4
    mm(As1, Bs1);   // f5
  }

  // ---- epilogue: per-wave LDS transpose -> coalesced full-line stores.
  // Each wave owns a 16x68 f32 region (4.25 KB): waves 0,1 in Bs0; 2,3 in Bs1.
  __syncthreads();                         // all mm reads of Bs done
  float* ep = (float*)(wn == 0 ? (void*)Bs0 : (void*)Bs1) + wm * 1152;
  // per-lane bias vector (cols seg*4..+3 of this wave's 64-col strip)
  float4 br4 = *(const float4*)&br[oBlock + wn * 64 + l15 * 4];
#pragma unroll
  for (int mi = 0; mi < 4; ++mi) {
    // scatter acc into [row 0..15][col 0..63] (row = kq*4+r, col = ni*16+l15)
#pragma unroll
    for (int ni = 0; ni < 4; ++ni)
#pragma unroll
      for (int r = 0; r < 4; ++r)
        ep[(kq * 4 + r) * 68 + ni * 16 + l15] = acc[mi][ni][r];
    // gather rows: pass p covers rows p*4+kq; lane l15 covers cols l15*4..+3
#pragma unroll
    for (int p = 0; p < 4; ++p) {
      int row = p * 4 + kq;
      float4 v = *(const float4*)&ep[row * 68 + l15 * 4];
      v.x += br4.x; v.y += br4.y; v.z += br4.z; v.w += br4.w;
      long grow = rBlock + wm * 64 + mi * 16 + row;
      *(float4*)&out[grow * 512 + oBlock + wn * 64 + l15 * 4] = v;
    }
  }
}

extern "C" void kernel_launch(void* const* d_in, const int* in_sizes, int n_in,
                              void* d_out, int out_size, void* d_ws,
                              size_t ws_size, hipStream_t stream) {
  (void)in_sizes; (void)n_in; (void)d_ws; (void)ws_size; (void)out_size;
  const float* x = (const float*)d_in[0];
  const float* We = (const float*)d_in[1];
  const float* be = (const float*)d_in[2];
  const float* omega = (const float*)d_in[3];
  const float* Wr = (const float*)d_in[4];
  const float* br = (const float*)d_in[5];

  float* out = (float*)d_out;
  float* logits = out;                               // [B,S,O] = [M,512]
  float* ph_hist = out + (long)M_DIM * O_DIM;        // [B,S,H] = [M,128]
  float* wb_hist = ph_hist + (long)M_DIM * H_DIM;    // [B,S,H]

  // scratch inside the (later overwritten) logits region:
  float* pt = logits;                                // [S,B,H] 16.8M floats
  int* rep = (int*)(logits + 40l * 1024 * 1024);     // 1024 ints, past pt

  prep_wrb<<<64, 256, 0, stream>>>(Wr);
  enc_kernel<<<M_DIM / 16, 256, 0, stream>>>(x, We, be, pt);
  rep_kernel<<<S_LEN, 256, 0, stream>>>(x, rep);
  scan_kernel<<<256, 64, 0, stream>>>(pt, omega, rep, ph_hist, wb_hist);
  out_mfma<<<4096, 256, 0, stream>>>(ph_hist, wb_hist, br, logits);
}

// Round 7
// 903.633 us; speedup vs baseline: 3.3866x; 1.2481x over previous
//
#include <hip/hip_runtime.h>
#include <math.h>

#define S_LEN 1024
#define B_DIM 128
#define D_DIM 64
#define H_DIM 128
#define O_DIM 512
#define M_DIM 131072         // B*S

// -------- kernel 1: encoder, 16 (b,t) pairs per block, We row in regs
__global__ __launch_bounds__(256) void enc_kernel(
    const float* __restrict__ x, const float* __restrict__ We,
    const float* __restrict__ be, float* __restrict__ pt) {
  __shared__ __align__(16) float xs[1024];
  int tid = threadIdx.x;
  long q0 = (long)blockIdx.x * 16;
  for (int i = tid; i < 1024; i += 256) xs[i] = x[q0 * 64 + i];
  __syncthreads();
  int h = tid & 127;
  int pg = tid >> 7;                       // 0/1: which 8 pairs
  float4 w[16];
  const float4* w4 = (const float4*)(We + (long)h * 64);
#pragma unroll
  for (int i = 0; i < 16; ++i) w[i] = w4[i];
  float bias = be[h];
#pragma unroll
  for (int j = 0; j < 8; ++j) {
    int p = pg * 8 + j;
    const float4* x4 = (const float4*)(xs + p * 64);
    float acc = 0.f;
#pragma unroll
    for (int i = 0; i < 16; ++i) {
      float4 a = x4[i];
      float4 b = w[i];
      acc += a.x * b.x + a.y * b.y + a.z * b.z + a.w * b.w;
    }
    long q = q0 + p;
    int bb = (int)(q >> 10), t = (int)(q & 1023);
    pt[(long)t * 16384 + bb * 128 + h] = acc + bias;
  }
}

// -------- kernel 2: is_rep[t] = all(x[:,t,:] == x[:,t-1,:]); rep[0]=0
__global__ __launch_bounds__(256) void rep_kernel(const float* __restrict__ x,
                                                  int* __restrict__ rep) {
  int t = blockIdx.x;
  int tid = threadIdx.x;
  if (t == 0) {
    if (tid == 0) rep[0] = 0;
    return;
  }
  int ok = 1;
  for (int j = tid; j < B_DIM * D_DIM; j += 256) {
    int b = j >> 6, d = j & 63;
    long i1 = (long)b * S_LEN * 64 + (long)t * 64 + d;
    if (x[i1] != x[i1 - 64]) ok = 0;
  }
  ok = __syncthreads_and(ok);
  if (tid == 0) rep[t] = ok;
}

// -------- kernel 3: sequential scan over t (math bit-identical; untouched)
__global__ __launch_bounds__(64) void scan_kernel(
    const float* __restrict__ pt, const float* __restrict__ omega,
    const int* __restrict__ rep, float* __restrict__ ph_out,
    float* __restrict__ wb_out) {
  __shared__ int reps[1024];
  int tid = threadIdx.x;
  for (int i = tid; i < 1024; i += 64) reps[i] = rep[i];
  __syncthreads();
  int g = blockIdx.x * 64 + tid;           // 0..16383
  int b = g >> 7, h = g & 127;
  float om = omega[h];
  float ph = 0.f, wb = 0.f;
  long obase = (long)b * (S_LEN * 128) + h;
  float cur[16], nxt[16];
#pragma unroll
  for (int u = 0; u < 16; ++u) cur[u] = pt[(long)u * 16384 + g];
  for (int t0 = 0; t0 < S_LEN; t0 += 16) {
#pragma unroll
    for (int u = 0; u < 16; ++u) {
      int tl = t0 + 16 + u;
      if (tl > 1023) tl = 1023;
      nxt[u] = pt[(long)tl * 16384 + g];
    }
#pragma unroll
    for (int u = 0; u < 16; ++u) {
      int t = t0 + u;
      float th = cur[u];
      wb += 0.015625f;
      ph = ph + om - sinf(th - ph) + 0.25f * sinf(wb);
      if (reps[t]) wb = wb + 0.25f * sinf(th - wb);
      ph_out[obase + (long)t * 128] = ph;
      wb_out[obase + (long)t * 128] = wb;
    }
#pragma unroll
    for (int u = 0; u < 16; ++u) cur[u] = nxt[u];
  }
}

// ---------------- bf16 helpers (RNE, bit-exact with previous rounds)
typedef short bf16x8 __attribute__((ext_vector_type(8)));
typedef float f32x4 __attribute__((ext_vector_type(4)));

__device__ __forceinline__ unsigned short bf_rne(float x) {
  union { float f; unsigned u; } c;
  c.f = x;
  unsigned u = c.u;
  return (unsigned short)((u + 0x7fffu + ((u >> 16) & 1u)) >> 16);
}
__device__ __forceinline__ float bf_to_f(unsigned short h) {
  union { unsigned u; float f; } c;
  c.u = ((unsigned)h) << 16;
  return c.f;
}

// Module-global scratch for pre-tiled bf16 Wr (1 MB). No d_ws dependency.
__device__ unsigned short g_Wrb[64 * 8192];

// -------- kernel 3.5: Wr -> bf16 tiles, once. XOR-SWIZZLED storage:
// physical short index = row*64 + (k ^ ((row&7)<<3)). gload_lds copies
// linearly, so LDS inherits the swizzle; ds_read applies the same XOR.
// Tile order: (cb, c), c = half*8 + j; j: 0=w7hi 1=w7lo 2=f2 3=f3 4=f0
// 5=f1 6=f4 7=f5. Tile = 128 rows (cols of C) x 64 k shorts (16 KB).
__global__ __launch_bounds__(256) void prep_wrb(const float* __restrict__ Wr) {
  int tile = blockIdx.x;                   // 0..63
  int cb = tile >> 4;
  int c = tile & 15;
  int half = (c >> 3) & 1;
  int j = c & 7;
  const int fmap[8] = {6, 6, 2, 3, 0, 1, 4, 5};   // f=6 -> col base 768 (=ph·w)
  int f = fmap[j];
  int tid = threadIdx.x;
  int row = tid >> 1;
  int k0 = (tid & 1) * 32;
  int xr = (row & 7) << 3;                 // XOR swizzle for this row
  const float* src = Wr + (long)(cb * 128 + row) * 896 + f * 128 + half * 64 + k0;
  unsigned short* dst = g_Wrb + (long)tile * 8192 + row * 64;
  int lo = (j == 1);
#pragma unroll
  for (int i = 0; i < 8; ++i) {
    float4 v = *(const float4*)&src[i * 4];
    float e[4] = {v.x, v.y, v.z, v.w};
    unsigned short q[4];
#pragma unroll
    for (int t = 0; t < 4; ++t) {
      unsigned short hb = bf_rne(e[t]);
      q[t] = lo ? bf_rne(e[t] - bf_to_f(hb)) : hb;
    }
    uint2 p;
    p.x = (unsigned)q[0] | ((unsigned)q[1] << 16);
    p.y = (unsigned)q[2] | ((unsigned)q[3] << 16);
    *(uint2*)&dst[(k0 + i * 4) ^ xr] = p;  // XOR flips bits 3..5 only: 4-grp ok
  }
}

typedef const void __attribute__((address_space(1))) gas_void;
typedef void __attribute__((address_space(3))) las_void;

// -------- kernel 4: MFMA readout GEMM. B staged via global_load_lds
// (zero-VGPR DMA of pre-swizzled g_Wrb; latency hidden under A trig),
// A = fused features with half-angle identities. Epilogue: per-wave LDS
// transpose in Bs -> full-line float4 stores.
__global__ __launch_bounds__(256, 2) void out_mfma(
    const float* __restrict__ ph_hist, const float* __restrict__ wb_hist,
    const float* __restrict__ br, float* __restrict__ out) {
  __shared__ __align__(16) unsigned short As0[128 * 72];
  __shared__ __align__(16) unsigned short As1[128 * 72];
  __shared__ __align__(16) unsigned short Bs0[128 * 64];
  __shared__ __align__(16) unsigned short Bs1[128 * 64];
  int tid = threadIdx.x;
  int lane = tid & 63;
  int wid = tid >> 6;
  int wm = wid >> 1, wn = wid & 1;         // 2x2 wave grid, 64x64 each
  // XCD chunk swizzle (bijective: 4096 % 8 == 0)
  int nb = ((blockIdx.x & 7) << 9) | (blockIdx.x >> 3);
  long rBlock = (long)(nb >> 2) * 128;
  int cb = nb & 3;
  int oBlock = cb * 128;
  int l15 = lane & 15;
  int kq = lane >> 4;                      // 0..3
  int jq = tid & 15;                       // k-quad: cols 4*jq..+4
  int r0 = tid >> 4;                       // A staging row base 0..15

  const unsigned short* wsrc = g_Wrb + (long)cb * (16 * 8192);

  f32x4 acc[4][4];
#pragma unroll
  for (int mi = 0; mi < 4; ++mi)
#pragma unroll
    for (int ni = 0; ni < 4; ++ni) {
      acc[mi][ni][0] = 0.f; acc[mi][ni][1] = 0.f;
      acc[mi][ni][2] = 0.f; acc[mi][ni][3] = 0.f;
    }

  // async B staging: tiles (2p, 2p+1) -> Bs0, Bs1. 16 chunks of 1024 B per
  // tile; wave w issues chunks w*4..w*4+3. LDS dest = uniform base + lane*16.
  auto stageB = [&](int p) {
    const unsigned short* t0 = wsrc + (long)(2 * p) * 8192;
    const unsigned short* t1 = wsrc + (long)(2 * p + 1) * 8192;
#pragma unroll
    for (int q = 0; q < 4; ++q) {
      int c = wid * 4 + q;
      int so = c * 512 + lane * 8;         // this lane's 16 B (shorts)
      __builtin_amdgcn_global_load_lds((gas_void*)(t0 + so),
                                       (las_void*)(Bs0 + c * 512), 16, 0, 0);
      __builtin_amdgcn_global_load_lds((gas_void*)(t1 + so),
                                       (las_void*)(Bs1 + c * 512), 16, 0, 0);
    }
  };
  auto storeA = [&](int i, uint2 v0, uint2 v1) {
    *(uint2*)&As0[(r0 + 16 * i) * 72 + 4 * jq] = v0;
    *(uint2*)&As1[(r0 + 16 * i) * 72 + 4 * jq] = v1;
  };
  auto pk = [&](float a, float b) -> unsigned {
    return (unsigned)bf_rne(a) | ((unsigned)bf_rne(b) << 16);
  };
  int xr = (l15 & 7) << 3;                 // B read-side XOR (row&7 == l15&7)
  auto mm = [&](const unsigned short* A, const unsigned short* Bsl) {
    __builtin_amdgcn_s_setprio(1);
#pragma unroll
    for (int ks = 0; ks < 2; ++ks) {
      int kk = ks * 32 + kq * 8;
      bf16x8 a[4], b[4];
#pragma unroll
      for (int mi = 0; mi < 4; ++mi)
        a[mi] = *(const bf16x8*)&A[(wm * 64 + mi * 16 + l15) * 72 + kk];
#pragma unroll
      for (int ni = 0; ni < 4; ++ni)
        b[ni] = *(const bf16x8*)&Bsl[(wn * 64 + ni * 16 + l15) * 64 + (kk ^ xr)];
#pragma unroll
      for (int mi = 0; mi < 4; ++mi)
#pragma unroll
        for (int ni = 0; ni < 4; ++ni)
          acc[mi][ni] = __builtin_amdgcn_mfma_f32_16x16x32_bf16(
              a[mi], b[ni], acc[mi][ni], 0, 0, 0);
    }
    __builtin_amdgcn_s_setprio(0);
  };

  float4 pha[8];
  // prologue: ph(half0) loads in flight
#pragma unroll
  for (int i = 0; i < 8; ++i)
    pha[i] = *(const float4*)&ph_hist[(rBlock + r0 + 16 * i) * 128 + 4 * jq];

#pragma unroll
  for (int half = 0; half < 2; ++half) {
    int h0 = half * 64;
    int pb = half * 4;

    // ---- p0: B(w7hi,w7lo) async; A = hi(ph), lo(ph)
    __syncthreads();                       // prev-phase Bs/As reads done
    stageB(pb + 0);
#pragma unroll
    for (int i = 0; i < 8; ++i) {
      float e[4] = {pha[i].x, pha[i].y, pha[i].z, pha[i].w};
      unsigned short hb[4], lb[4];
#pragma unroll
      for (int t = 0; t < 4; ++t) {
        hb[t] = bf_rne(e[t]);
        lb[t] = bf_rne(e[t] - bf_to_f(hb[t]));
      }
      uint2 vh, vl;
      vh.x = (unsigned)hb[0] | ((unsigned)hb[1] << 16);
      vh.y = (unsigned)hb[2] | ((unsigned)hb[3] << 16);
      vl.x = (unsigned)lb[0] | ((unsigned)lb[1] << 16);
      vl.y = (unsigned)lb[2] | ((unsigned)lb[3] << 16);
      storeA(i, vh, vl);
    }
    __syncthreads();                       // drains gload_lds + ds_writes
    mm(As0, Bs0);   // f6: hi·hi
    mm(As1, Bs0);   // f7: lo·hi
    mm(As0, Bs1);   // f8: hi·lo

    // ---- p1: B(f2,f3) async; one sincos(ph/2): A = f2,f3; derive f0,f1
    __syncthreads();
    stageB(pb + 1);
    uint2 f0p[8], f1p[8];
#pragma unroll
    for (int i = 0; i < 8; ++i) {
      float e[4] = {pha[i].x, pha[i].y, pha[i].z, pha[i].w};
      float s2[4], c2[4], cf[4], sf[4];
#pragma unroll
      for (int t = 0; t < 4; ++t) {
        __sincosf(0.5f * e[t], &s2[t], &c2[t]);
        cf[t] = fmaf(-2.f * s2[t], s2[t], 1.f);   // cos(ph) = 1 - 2 sin^2(ph/2)
        sf[t] = 2.f * s2[t] * c2[t];              // sin(ph) = 2 sc
      }
      uint2 vc, vs;
      vc.x = pk(c2[0], c2[1]); vc.y = pk(c2[2], c2[3]);
      vs.x = pk(s2[0], s2[1]); vs.y = pk(s2[2], s2[3]);
      storeA(i, vc, vs);
      f0p[i].x = pk(cf[0], cf[1]); f0p[i].y = pk(cf[2], cf[3]);
      f1p[i].x = pk(sf[0], sf[1]); f1p[i].y = pk(sf[2], sf[3]);
    }
    __syncthreads();
    mm(As0, Bs0);   // f2
    mm(As1, Bs1);   // f3

    // ---- p2: B(f0,f1) async; A = f0,f1 (precomputed); prefetch wb
    __syncthreads();
    stageB(pb + 2);
#pragma unroll
    for (int i = 0; i < 8; ++i) storeA(i, f0p[i], f1p[i]);
#pragma unroll
    for (int i = 0; i < 8; ++i)
      pha[i] = *(const float4*)&wb_hist[(rBlock + r0 + 16 * i) * 128 + h0 + 4 * jq];
    __syncthreads();
    mm(As0, Bs0);   // f0
    mm(As1, Bs1);   // f1

    // ---- p3: B(f4,f5) async; A = cos(wb), sin(wb); prefetch ph(half1)
    __syncthreads();
    stageB(pb + 3);
#pragma unroll
    for (int i = 0; i < 8; ++i) {
      float e[4] = {pha[i].x, pha[i].y, pha[i].z, pha[i].w};
      float sn[4], cs[4];
#pragma unroll
      for (int t = 0; t < 4; ++t) __sincosf(e[t], &sn[t], &cs[t]);
      uint2 vc, vs;
      vc.x = pk(cs[0], cs[1]); vc.y = pk(cs[2], cs[3]);
      vs.x = pk(sn[0], sn[1]); vs.y = pk(sn[2], sn[3]);
      storeA(i, vc, vs);
    }
    if (half == 0) {
#pragma unroll
      for (int i = 0; i < 8; ++i)
        pha[i] = *(const float4*)&ph_hist[(rBlock + r0 + 16 * i) * 128 + 64 + 4 * jq];
    }
    __syncthreads();
    mm(As0, Bs0);   // f4
    mm(As1, Bs1);   // f5
  }

  // ---- epilogue: per-wave LDS transpose -> coalesced full-line stores.
  // Each wave owns a 16x68 f32 region: waves wn==0 in Bs0, wn==1 in Bs1
  // (Bs = 16 KB each; 2 waves x 1152 floats = 9216 B fits).
  __syncthreads();                         // all mm reads of Bs done
  float* ep = (float*)(wn == 0 ? (void*)Bs0 : (void*)Bs1) + wm * 1152;
  float4 br4 = *(const float4*)&br[oBlock + wn * 64 + l15 * 4];
#pragma unroll
  for (int mi = 0; mi < 4; ++mi) {
#pragma unroll
    for (int ni = 0; ni < 4; ++ni)
#pragma unroll
      for (int r = 0; r < 4; ++r)
        ep[(kq * 4 + r) * 68 + ni * 16 + l15] = acc[mi][ni][r];
#pragma unroll
    for (int p = 0; p < 4; ++p) {
      int row = p * 4 + kq;
      float4 v = *(const float4*)&ep[row * 68 + l15 * 4];
      v.x += br4.x; v.y += br4.y; v.z += br4.z; v.w += br4.w;
      long grow = rBlock + wm * 64 + mi * 16 + row;
      *(float4*)&out[grow * 512 + oBlock + wn * 64 + l15 * 4] = v;
    }
  }
}

extern "C" void kernel_launch(void* const* d_in, const int* in_sizes, int n_in,
                              void* d_out, int out_size, void* d_ws,
                              size_t ws_size, hipStream_t stream) {
  (void)in_sizes; (void)n_in; (void)d_ws; (void)ws_size; (void)out_size;
  const float* x = (const float*)d_in[0];
  const float* We = (const float*)d_in[1];
  const float* be = (const float*)d_in[2];
  const float* omega = (const float*)d_in[3];
  const float* Wr = (const float*)d_in[4];
  const float* br = (const float*)d_in[5];

  float* out = (float*)d_out;
  float* logits = out;                               // [B,S,O] = [M,512]
  float* ph_hist = out + (long)M_DIM * O_DIM;        // [B,S,H] = [M,128]
  float* wb_hist = ph_hist + (long)M_DIM * H_DIM;    // [B,S,H]

  // scratch inside the (later overwritten) logits region:
  float* pt = logits;                                // [S,B,H] 16.8M floats
  int* rep = (int*)(logits + 40l * 1024 * 1024);     // 1024 ints, past pt

  prep_wrb<<<64, 256, 0, stream>>>(Wr);
  enc_kernel<<<M_DIM / 16, 256, 0, stream>>>(x, We, be, pt);
  rep_kernel<<<S_LEN, 256, 0, stream>>>(x, rep);
  scan_kernel<<<256, 64, 0, stream>>>(pt, omega, rep, ph_hist, wb_hist);
  out_mfma<<<4096, 256, 0, stream>>>(ph_hist, wb_hist, br, logits);
}